// Round 2
// baseline (220.897 us; speedup 1.0000x reference)
//
#include <hip/hip_runtime.h>
#include <hip/hip_fp16.h>
#include <cstddef>

// AffinityPropagate: per-pixel normalized 3x3 stencil, 24 steps.
// R7: TWO steps per barrier. Each wave reads a 12x3 input window (36 ds_read,
// one latency window), computes 10 intermediate rows IN REGISTERS (weights
// extended to 10 overlapping rows/thread), gets neighbor-column intermediates
// via 20 __shfl_up/down (no LDS), computes 8 final rows, writes 8, ONE
// barrier. Per 2 steps: barriers 2->1, LDS ops 76->64, FMA 144->162.
// R6 post-mortem: both dispatches ~80us regardless of HBM traffic; VALU ~23K
// cy + LDS ~43K cy vs 193K wall -> sync/latency-convoy bound on the 12
// per-step barriers, not any throughput pipe. This halves the sync points.
//
// Ring math (staged coords, halo 13 => staged rows/cols 0..65, weight region
// staged 1..64): valid ring after step s is [s, 65-s]. Period p (2 steps)
// produces finals valid on [2p+2, 63-2p]. Wave g writes staged rows
// 8g+1..8g+8. Intermediates at slab edges (staged rows 8g, 8g+9) and shuffle
// garbage at cols 1/64 only pollute outputs already outside the ring.
// Out-of-image px have all-zero weights -> stay exactly 0 = zero padding.
// LDS buffers have a guard row top+bottom (stored row = staged row + 1,
// 68 rows) so edge waves read in-bounds zeros.
//
// Tap order: w0=NW w1=N w2=NE w3=W [center] w4=E w5=SW w6=S w7=SE

#define HIMG 480
#define WIMG 640
#define HW   (HIMG * WIMG)
#define BN   8

#define TILE   40
#define TSTEPS 12
#define NPER   6                 // barrier periods (2 steps each)
#define IH     13                // staged halo
#define WHL    12                // weight halo
#define SW     66                // staged rows/cols
#define ROWS   68                // stored rows (guard top+bottom)
#define PITCH  68                // LDS row pitch (floats)
#define NT     512

#define WS_FRAME_B  ((size_t)BN * HW * 4)            // 9,830,400
#define WS_WA_B     ((size_t)BN * HW * 16)           // 39,321,600
#define WS_WC_B     ((size_t)BN * HW * 4)            // 9,830,400
#define WS_NEED     (WS_FRAME_B + WS_WA_B + WS_WC_B) // 58,982,400

// MODE: 0 = normalize in-kernel + store interior weights to wA/wC
//       1 = load packed weights from wA/wC
//       2 = normalize in-kernel, no store (fallback when ws too small)
template <int MODE>
__global__ __launch_bounds__(NT, 4) void affprop12(
    const float* __restrict__ aff,
    __half2* __restrict__ wA,
    float* __restrict__ wC,
    const float* __restrict__ src,
    float* __restrict__ dst)
{
    __shared__ float fA[ROWS * PITCH];
    __shared__ float fB[ROWS * PITCH];

    const int tid = threadIdx.x;
    const int ox  = blockIdx.x * TILE;
    const int oy  = blockIdx.y * TILE;
    const int b   = blockIdx.z;

    const float* __restrict__ sb = src + (size_t)b * HW;
    float*       __restrict__ db = dst + (size_t)b * HW;

    // ---- stage input region [oy-13, oy+53) x [ox-13, ox+53) into stored
    //      rows 1..66; 0 outside image
    for (int i = tid; i < SW * SW; i += NT) {
        int r  = i / SW;
        int c  = i - r * SW;
        int gy = oy - IH + r;
        int gx = ox - IH + c;
        float v = 0.f;
        if ((unsigned)gy < (unsigned)HIMG && (unsigned)gx < (unsigned)WIMG)
            v = sb[gy * WIMG + gx];
        fA[(r + 1) * PITCH + c] = v;
    }
    // ---- zero guard rows of fA (stored rows 0 and 67)
    for (int i = tid; i < 2 * PITCH; i += NT) {
        int r = (i < PITCH) ? 0 : (ROWS - 1);
        int c = (i < PITCH) ? i : i - PITCH;
        fA[r * PITCH + c] = 0.f;
    }
    // ---- zero-fill buffer B (deterministic stale rings + guard rows)
    for (int i = tid; i < ROWS * PITCH / 4; i += NT)
        *(float4*)&fB[4 * i] = make_float4(0.f, 0.f, 0.f, 0.f);

    // ---- per-thread: weight column c, row group g; 10 overlapping weight
    //      rows j=0..9 <-> weight-region rows 8g-1..8g+8 (staged 8g..8g+9)
    const int c  = tid & 63;          // weight col 0..63
    const int g  = tid >> 6;          // row group 0..7
    const int sc = c + 1;             // staged col of this thread's outputs

    __half2 wv[10][4];  // [row j][tap pair (01)(23)(45)(67)]
    float   wcc[10];    // center weights (f32)

    #pragma unroll
    for (int j = 0; j < 10; ++j) {
        const int gy = oy - WHL + 8 * g - 1 + j;
        const int gx = ox - WHL + c;
        const bool in = (unsigned)gy < (unsigned)HIMG && (unsigned)gx < (unsigned)WIMG;
        const size_t idx = (size_t)b * HW + (size_t)gy * WIMG + gx;

        if (MODE == 1) {
            if (in) {
                union { float4 f4; __half2 h[4]; } u;
                u.f4 = *(const float4*)(wA + 4 * idx);
                wv[j][0] = u.h[0]; wv[j][1] = u.h[1];
                wv[j][2] = u.h[2]; wv[j][3] = u.h[3];
                wcc[j] = wC[idx];
            } else {
                __half2 z = __floats2half2_rn(0.f, 0.f);
                wv[j][0] = z; wv[j][1] = z; wv[j][2] = z; wv[j][3] = z;
                wcc[j] = 0.f;
            }
        } else {
            float w[8];
            float s = 0.f;
            if (in) {
                const float* ap = aff + (size_t)b * 8 * HW + (size_t)gy * WIMG + gx;
                #pragma unroll
                for (int k = 0; k < 8; ++k) { w[k] = ap[(size_t)k * HW]; s += fabsf(w[k]); }
            } else {
                #pragma unroll
                for (int k = 0; k < 8; ++k) w[k] = 0.f;
                s = 1.f;
            }
            float rr  = in ? 1.0f / s : 0.f;
            float acc = 0.f;
            #pragma unroll
            for (int k = 0; k < 8; ++k) { w[k] *= rr; acc += w[k]; }

            union { float4 f4; __half2 h[4]; } u;
            u.h[0] = __floats2half2_rn(w[0], w[1]);
            u.h[1] = __floats2half2_rn(w[2], w[3]);
            u.h[2] = __floats2half2_rn(w[4], w[5]);
            u.h[3] = __floats2half2_rn(w[6], w[7]);
            wv[j][0] = u.h[0]; wv[j][1] = u.h[1];
            wv[j][2] = u.h[2]; wv[j][3] = u.h[3];
            wcc[j] = in ? 1.0f - acc : 0.f;

            if (MODE == 0) {
                // store interior weights for launch 2; only j=1..8 (the
                // non-overlapping rows) so each px is stored exactly once
                if (j >= 1 && j <= 8 &&
                    (unsigned)(gy - oy) < (unsigned)TILE &&
                    (unsigned)(gx - ox) < (unsigned)TILE) {
                    *(float4*)(wA + 4 * idx) = u.f4;
                    wC[idx] = wcc[j];
                }
            }
        }
    }
    __syncthreads();

    // ---- 6 periods x 2 fused steps; intermediates in registers + shuffles
    const float* fin = fA;
    float*       fo  = fB;

    #pragma unroll 1
    for (int p = 0; p < NPER; ++p) {
        // wave-uniform liveness: finals (staged rows 8g+1..8g+8) intersect
        // the ring [2p+2, 63-2p] needed after this period
        const bool live = (8 * g + 8 >= 2 * p + 2) && (8 * g + 1 <= 63 - 2 * p);
        if (live) {
            // reads: staged rows 8g-1..8g+10 = stored rows 8g..8g+11
            const float* bp = fin + (8 * g) * PITCH + c;
            float u0[12], u1[12], u2[12];
            #pragma unroll
            for (int k = 0; k < 12; ++k) {
                u0[k] = bp[k * PITCH + 0];
                u1[k] = bp[k * PITCH + 1];
                u2[k] = bp[k * PITCH + 2];
            }
            // sub-step A: 10 intermediate rows (staged 8g+j) in registers
            float m[10];
            #pragma unroll
            for (int j = 0; j < 10; ++j) {
                m[j] = wcc[j] * u1[j + 1]
                    + __low2float (wv[j][0]) * u0[j]        // NW
                    + __high2float(wv[j][0]) * u1[j]        // N
                    + __low2float (wv[j][1]) * u2[j]        // NE
                    + __high2float(wv[j][1]) * u0[j + 1]    // W
                    + __low2float (wv[j][2]) * u2[j + 1]    // E
                    + __high2float(wv[j][2]) * u0[j + 2]    // SW
                    + __low2float (wv[j][3]) * u1[j + 2]    // S
                    + __high2float(wv[j][3]) * u2[j + 2];   // SE
            }
            // neighbor columns via cross-lane (lane c-1 / c+1); edge-lane
            // garbage lands only in cols 1/64 = never-valid ring
            float mL[10], mR[10];
            #pragma unroll
            for (int j = 0; j < 10; ++j) {
                mL[j] = __shfl_up(m[j], 1);
                mR[j] = __shfl_down(m[j], 1);
            }
            // sub-step B: 8 final rows (staged 8g+1+i = stored 8g+2+i)
            float* wp = fo + (8 * g + 2) * PITCH + sc;
            #pragma unroll
            for (int i = 0; i < 8; ++i) {
                float o = wcc[i + 1] * m[i + 1]
                    + __low2float (wv[i + 1][0]) * mL[i]        // NW
                    + __high2float(wv[i + 1][0]) * m[i]         // N
                    + __low2float (wv[i + 1][1]) * mR[i]        // NE
                    + __high2float(wv[i + 1][1]) * mL[i + 1]    // W
                    + __low2float (wv[i + 1][2]) * mR[i + 1]    // E
                    + __high2float(wv[i + 1][2]) * mL[i + 2]    // SW
                    + __low2float (wv[i + 1][3]) * m[i + 2]     // S
                    + __high2float(wv[i + 1][3]) * mR[i + 2];   // SE
                wp[i * PITCH] = o;
            }
        }
        __syncthreads();
        const float* t = fin; fin = fo; fo = (float*)t;
    }

    // ---- store 40x40 tile (fin == fA after 6 periods);
    //      staged row 13+r = stored row 14+r
    for (int i = tid; i < TILE * (TILE / 4); i += NT) {
        int r  = i / (TILE / 4);
        int c4 = (i - r * (TILE / 4)) * 4;
        const float* p = fin + (IH + 1 + r) * PITCH + IH + c4;
        float4 v = make_float4(p[0], p[1], p[2], p[3]);
        *(float4*)&db[(size_t)(oy + r) * WIMG + ox + c4] = v;
    }
}

extern "C" void kernel_launch(void* const* d_in, const int* in_sizes, int n_in,
                              void* d_out, int out_size, void* d_ws, size_t ws_size,
                              hipStream_t stream)
{
    const float* aff  = (const float*)d_in[0];
    const float* feat = (const float*)d_in[1];
    float* out = (float*)d_out;

    char* ws = (char*)d_ws;
    float*   wsFrame = (float*)ws;
    __half2* wA      = (__half2*)(ws + WS_FRAME_B);
    float*   wC      = (float*)(ws + WS_FRAME_B + WS_WA_B);

    dim3 blk(NT, 1, 1);
    dim3 grd(WIMG / TILE, HIMG / TILE, BN);   // 16 x 12 x 8 = 1536 blocks

    if (ws_size >= WS_NEED) {
        affprop12<0><<<grd, blk, 0, stream>>>(aff, wA, wC, feat, wsFrame);
        affprop12<1><<<grd, blk, 0, stream>>>(aff, wA, wC, wsFrame, out);
    } else {
        affprop12<2><<<grd, blk, 0, stream>>>(aff, nullptr, nullptr, feat, wsFrame);
        affprop12<2><<<grd, blk, 0, stream>>>(aff, nullptr, nullptr, wsFrame, out);
    }
}